// Round 2
// baseline (2823.503 us; speedup 1.0000x reference)
//
#include <hip/hip_runtime.h>
#include <math.h>

#define EPS 1e-6f

__device__ __forceinline__ float bcast(float x, int srcLane) {
    return __int_as_float(__builtin_amdgcn_readlane(__float_as_int(x), srcLane));
}

// Packed lower-triangular storage for L_B in LDS, each column 16B-aligned:
// column k (rows k..63) starts at off16(k), size align4(64-k). Total 2176
// floats + 64 dump slots for lanes<k on the column write.
constexpr int WCOLS = 2176;
constexpr int WSLOT = WCOLS + 64;  // 2240 floats = 8960 B per wave (16B mult)

// Round 5: LDS-broadcast instead of readlane-broadcast for both Cholesky
// rank-1 updates (uniform-address ds_read_b128 = 4 broadcast scalars per
// LDS-pipe op -> 1 fma/element on the VALU instead of readlane+fma), plus
// freeze-trick Frobenius (mask t=0 for lane<=k so each lane's row registers
// freeze at their u-values; fro becomes a masked epilogue) removing the 2080
// per-element acc fmas. ~16k -> ~10k VALU instr/wave. Fusion with enc
// reverted (round 4: both kernels issue-bound, fusion net -19 us).
__global__ __launch_bounds__(256, 1) void vae_rec_kernel(const float* __restrict__ recon,
                                                         const float* __restrict__ orig,
                                                         float* __restrict__ out,
                                                         int npairs) {
    const int lane = threadIdx.x & 63;
    const int waveInBlock = threadIdx.x >> 6;
    const int pair = blockIdx.x * 4 + waveInBlock;

    __shared__ __align__(16) float lds[4 * WSLOT];
    __shared__ __align__(16) float lacol[4][64];
    float* wl = lds + waveInBlock * WSLOT;
    float* lc = lacol[waveInBlock];

    float kl = 0.0f;
    if (pair < npairs) {
        const float* Bm = recon + (size_t)pair * 4096;
        const float* Am = orig + (size_t)pair * 4096;

        // ---- Phase 1: load B, Cholesky(B), columns staged+broadcast via LDS ----
        float detB;
        {
            float rB[64];
            const float4* pb = (const float4*)(Bm + lane * 64);
#pragma unroll
            for (int i = 0; i < 16; ++i) {
                float4 v = pb[i];
                rB[4 * i + 0] = v.x; rB[4 * i + 1] = v.y;
                rB[4 * i + 2] = v.z; rB[4 * i + 3] = v.w;
            }
            detB = 1.0f;
            int off = 0;  // constant-folded by full unroll
#pragma unroll
            for (int k = 0; k < 64; ++k) {
                float bkk = bcast(rB[k], k);
                detB *= bkk;
                float ib = __builtin_amdgcn_rsqf(bkk);
                float lk = rB[k] * ib;  // L_B[lane][k], valid for lane >= k
                int widx = (lane >= k) ? (off + lane - k) : (WCOLS + lane);
                wl[widx] = lk;
                if (k < 63) {
                    const int nq = (64 - k + 3) >> 2;
#pragma unroll
                    for (int t = 0; t < nq; ++t) {
                        float4 q = *reinterpret_cast<const float4*>(wl + off + 4 * t);
                        const int j0 = k + 4 * t;
                        if (j0 + 0 > k && j0 + 0 < 64) rB[j0 + 0] = __builtin_fmaf(-lk, q.x, rB[j0 + 0]);
                        if (j0 + 1 > k && j0 + 1 < 64) rB[j0 + 1] = __builtin_fmaf(-lk, q.y, rB[j0 + 1]);
                        if (j0 + 2 > k && j0 + 2 < 64) rB[j0 + 2] = __builtin_fmaf(-lk, q.z, rB[j0 + 2]);
                        if (j0 + 3 > k && j0 + 3 < 64) rB[j0 + 3] = __builtin_fmaf(-lk, q.w, rB[j0 + 3]);
                    }
                }
                off += (64 - k + 3) & ~3;
            }
        }  // rB dead here

        // ---- Phase 2: load A; fused Cholesky(A) + forward substitution ----
        float rA[64];
        {
            const float4* pa = (const float4*)(Am + lane * 64);
#pragma unroll
            for (int i = 0; i < 16; ++i) {
                float4 v = pa[i];
                rA[4 * i + 0] = v.x; rA[4 * i + 1] = v.y;
                rA[4 * i + 2] = v.z; rA[4 * i + 3] = v.w;
            }
        }
        float detA = 1.0f;
        int off = 0;
#pragma unroll
        for (int k = 0; k < 64; ++k) {
            // Cholesky(A) step k
            float akk = bcast(rA[k], k);
            detA *= akk;
            float ia = __builtin_amdgcn_rsqf(akk);
            rA[k] *= ia;          // finalize column k of L_A (lanes >= k)
            float lka = rA[k];    // capture BEFORE subst's c2=k update
            lc[lane] = lka;       // stage column k for uniform broadcast reads
            // Substitution step k: row k of W = L_B^{-1} L_A (independent of
            // the lc round-trip; compiler hides the lgkm latency under it).
            float cB = wl[off + lane - k];  // lanes<k read harmless garbage
            float bii = bcast(cB, k);       // = L_B[k][k]
            float inv = __builtin_amdgcn_rcpf(bii);
            // freeze: lanes <= k stop updating -> their row regs keep the
            // u-values of their own step; fro recovered in the epilogue.
            float tt = (lane > k) ? (cB * inv) : 0.0f;
#pragma unroll
            for (int c2 = 0; c2 <= k; ++c2) {
                float u = bcast(rA[c2], k);              // residual row k (uniform)
                rA[c2] = __builtin_fmaf(-tt, u, rA[c2]); // update rows > k
            }
            // Cholesky trailing update from uniform LDS quads
            if (k < 63) {
#pragma unroll
                for (int t = (k >> 2); t < 16; ++t) {
                    float4 q = *reinterpret_cast<const float4*>(lc + 4 * t);
                    const int j0 = 4 * t;
                    if (j0 + 0 > k && j0 + 0 < 64) rA[j0 + 0] = __builtin_fmaf(-lka, q.x, rA[j0 + 0]);
                    if (j0 + 1 > k && j0 + 1 < 64) rA[j0 + 1] = __builtin_fmaf(-lka, q.y, rA[j0 + 1]);
                    if (j0 + 2 > k && j0 + 2 < 64) rA[j0 + 2] = __builtin_fmaf(-lka, q.z, rA[j0 + 2]);
                    if (j0 + 3 > k && j0 + 3 < 64) rA[j0 + 3] = __builtin_fmaf(-lka, q.w, rA[j0 + 3]);
                }
            }
            off += (64 - k + 3) & ~3;
        }

        // Epilogue: frolane = ||row lane of (pre-diag-scaled W)||^2 * inv_diag^2
        // off16(m) = 64m - m(m-1)/2 + sum_{j<m}(j&3); diag L_B[m][m] is the
        // first element of packed column m in wl.
        const int m = lane;
        const int offm = ((m * (129 - m)) >> 1) + 6 * (m >> 2) + ((0x3100 >> ((m & 3) << 2)) & 0xF);
        float dm = wl[offm];
        float invm = __builtin_amdgcn_rcpf(dm);
        float fr = 0.0f;
#pragma unroll
        for (int c = 0; c < 64; ++c) {
            float v = (c <= lane) ? rA[c] : 0.0f;  // c>lane regs hold garbage
            fr = __builtin_fmaf(v, v, fr);
        }
        fr = fr * invm * invm;
#pragma unroll
        for (int s = 1; s < 64; s <<= 1) fr += __shfl_xor(fr, s, 64);

        float sdetB = __builtin_sqrtf(detB);
        float sdetA = __builtin_sqrtf(detA);
        float logdet = __builtin_logf((sdetA + EPS) / (sdetB + EPS));
        kl = 0.5f * (fr - 64.0f + logdet);
    }

    __shared__ float sred[4];
    if (lane == 0) sred[waveInBlock] = kl;
    __syncthreads();
    if (threadIdx.x == 0) {
        float s = sred[0] + sred[1] + sred[2] + sred[3];
        atomicAdd(out + 1, -s);
    }
}

// Encoded: 32x32 Cholesky (sqrt-det) + trace. Two matrices per wave (lanes
// 0-31 / 32-63); rank-1 broadcast via per-half uniform ds_read_b128 quads.
__global__ __launch_bounds__(256, 1) void vae_enc_kernel(const float* __restrict__ enc,
                                                         float* __restrict__ out,
                                                         int nmats) {
    const int lane = threadIdx.x & 63;
    const int r = lane & 31;
    const bool hi = lane >= 32;
    const int wv = (int)(blockIdx.x * 4 + (threadIdx.x >> 6));
    const int mat = wv * 2 + (hi ? 1 : 0);

    __shared__ __align__(16) float ecol[4][64];
    float* ec = ecol[threadIdx.x >> 6];
    const float* ebase = ec + (hi ? 32 : 0);

    float kl = 0.0f;
    if (mat < nmats) {
        const float* M = enc + (size_t)mat * 1024;
        float rm[32];
        {
            const float4* pm = (const float4*)(M + r * 32);
#pragma unroll
            for (int i = 0; i < 8; ++i) {
                float4 v = pm[i];
                rm[4 * i + 0] = v.x; rm[4 * i + 1] = v.y;
                rm[4 * i + 2] = v.z; rm[4 * i + 3] = v.w;
            }
        }

        float tr = 0.0f;
#pragma unroll
        for (int i = 0; i < 32; ++i)
            if (i == r) tr = rm[i];
#pragma unroll
        for (int m = 1; m < 32; m <<= 1)
            tr += __shfl_xor(tr, m, 64);

        float det = 1.0f;
#pragma unroll
        for (int k = 0; k < 32; ++k) {
            float a0 = bcast(rm[k], k);
            float a1 = bcast(rm[k], k + 32);
            float akk = hi ? a1 : a0;
            det *= akk;
            float inv = __builtin_amdgcn_rsqf(akk);
            rm[k] *= inv;
            ec[lane] = rm[k];  // stage both halves' columns
            if (k < 31) {
#pragma unroll
                for (int t = (k >> 2); t < 8; ++t) {
                    float4 q = *reinterpret_cast<const float4*>(ebase + 4 * t);
                    const int j0 = 4 * t;
                    if (j0 + 0 > k) rm[j0 + 0] = __builtin_fmaf(-rm[k], q.x, rm[j0 + 0]);
                    if (j0 + 1 > k) rm[j0 + 1] = __builtin_fmaf(-rm[k], q.y, rm[j0 + 1]);
                    if (j0 + 2 > k) rm[j0 + 2] = __builtin_fmaf(-rm[k], q.z, rm[j0 + 2]);
                    if (j0 + 3 > k) rm[j0 + 3] = __builtin_fmaf(-rm[k], q.w, rm[j0 + 3]);
                }
            }
        }

        float sdet = __builtin_sqrtf(det);
        float logdet = __builtin_logf((sdet + EPS) / (1.0f + EPS));
        kl = 0.5f * (tr - 32.0f + logdet);
    }

    __shared__ float sred[8];
    if (r == 0) sred[threadIdx.x >> 5] = kl;
    __syncthreads();
    if (threadIdx.x == 0) {
        float s = 0.0f;
#pragma unroll
        for (int i = 0; i < 8; ++i) s += sred[i];
        atomicAdd(out + 2, -s);
    }
}

__global__ void vae_init_kernel(float* __restrict__ out) {
    if (threadIdx.x < 3) out[threadIdx.x] = 0.0f;
}

__global__ void vae_final_kernel(float* __restrict__ out) {
    if (threadIdx.x == 0) out[0] = out[1] + out[2];
}

extern "C" void kernel_launch(void* const* d_in, const int* in_sizes, int n_in,
                              void* d_out, int out_size, void* d_ws, size_t ws_size,
                              hipStream_t stream) {
    const float* recon = (const float*)d_in[0];
    const float* orig = (const float*)d_in[1];
    const float* enc = (const float*)d_in[2];
    float* out = (float*)d_out;

    const int npairs = in_sizes[0] / 4096;   // 8192
    const int nmats = in_sizes[2] / 1024;    // 8192

    vae_init_kernel<<<1, 64, 0, stream>>>(out);

    const int rec_blocks = (npairs + 3) / 4;          // 4 waves/block, 1 pair/wave
    vae_rec_kernel<<<rec_blocks, 256, 0, stream>>>(recon, orig, out, npairs);

    const int enc_blocks = (nmats + 7) / 8;           // 8 matrices/block (2 per wave)
    vae_enc_kernel<<<enc_blocks, 256, 0, stream>>>(enc, out, nmats);

    vae_final_kernel<<<1, 64, 0, stream>>>(out);
}

// Round 3
// 447.260 us; speedup vs baseline: 6.3129x; 6.3129x over previous
//
#include <hip/hip_runtime.h>
#include <math.h>

#define EPS 1e-6f

__device__ __forceinline__ float bcast(float x, int srcLane) {
    return __int_as_float(__builtin_amdgcn_readlane(__float_as_int(x), srcLane));
}

// Packed lower-triangular storage for L_B in LDS: column k (rows k..63) at
// offset off(k) = sum_{j<k}(64-j) = k*(129-k)/2; 2080 floats + 64 dump slots.
constexpr int TRI = 2080;
constexpr int WSLOT = TRI + 64;  // 8576 B per wave

// Round 6 = round-3 structure (known-good 258 us) + freeze-trick Frobenius
// ONLY. Round 5's LDS-quad broadcast hit the predicted -40% instr count but
// its 16 hoisted float4 temps per k-step spilled rA/rB to scratch (WRITE_SIZE
// 64KB -> 9GB, 10x slower). The freeze trick is the register-neutral part:
// mask t=0 for lane<=k so each lane's row regs freeze at its own row's
// unscaled W values; the 2080 in-loop acc-fmas become a ~200-op epilogue
// (sum rA[c]^2 * rcp(diag)^2, diag re-read from packed LDS).
__global__ __launch_bounds__(256, 1) void vae_rec_kernel(const float* __restrict__ recon,
                                                         const float* __restrict__ orig,
                                                         float* __restrict__ out,
                                                         int npairs) {
    const int lane = threadIdx.x & 63;
    const int waveInBlock = threadIdx.x >> 6;
    const int pair = blockIdx.x * 4 + waveInBlock;

    __shared__ float lds[4 * WSLOT];
    float* wl = lds + waveInBlock * WSLOT;

    float kl = 0.0f;
    if (pair < npairs) {
        const float* Bm = recon + (size_t)pair * 4096;
        const float* Am = orig + (size_t)pair * 4096;

        // ---- Phase 1: load B, Cholesky(B), stage columns to LDS ----
        float detB;
        {
            float rB[64];
            const float4* pb = (const float4*)(Bm + lane * 64);
#pragma unroll
            for (int i = 0; i < 16; ++i) {
                float4 v = pb[i];
                rB[4 * i + 0] = v.x; rB[4 * i + 1] = v.y;
                rB[4 * i + 2] = v.z; rB[4 * i + 3] = v.w;
            }
            detB = 1.0f;
            int off = 0;  // constant-folded by full unroll
#pragma unroll
            for (int k = 0; k < 64; ++k) {
                float bkk = bcast(rB[k], k);
                detB *= bkk;
                float ib = __builtin_amdgcn_rsqf(bkk);
                float lk = rB[k] * ib;  // L_B[lane][k], valid for lane >= k
                // packed column write; lanes < k go to the dump region
                int idx = (lane >= k) ? (off + lane - k) : (TRI + lane);
                wl[idx] = lk;
                off += 64 - k;
#pragma unroll
                for (int j = k + 1; j < 64; ++j) {
                    float c = bcast(lk, j);  // L_B[j][k]
                    rB[j] = __builtin_fmaf(-lk, c, rB[j]);
                }
            }
        }  // rB dead here

        // ---- Phase 2: load A; fused Cholesky(A) + forward substitution ----
        float rA[64];
        {
            const float4* pa = (const float4*)(Am + lane * 64);
#pragma unroll
            for (int i = 0; i < 16; ++i) {
                float4 v = pa[i];
                rA[4 * i + 0] = v.x; rA[4 * i + 1] = v.y;
                rA[4 * i + 2] = v.z; rA[4 * i + 3] = v.w;
            }
        }
        float detA = 1.0f;
        int off = 0;
#pragma unroll
        for (int k = 0; k < 64; ++k) {
            // Cholesky(A) step k
            float akk = bcast(rA[k], k);
            detA *= akk;
            float ia = __builtin_amdgcn_rsqf(akk);
            rA[k] *= ia;  // finalize column k of L_A (lanes >= k)
#pragma unroll
            for (int j = k + 1; j < 64; ++j) {
                float c = bcast(rA[k], j);
                rA[j] = __builtin_fmaf(-rA[k], c, rA[j]);
            }
            // Substitution step k: row k of W = L_B^{-1} L_A.
            int idx = off + ((lane >= k) ? (lane - k) : 0);  // sub-k lanes: broadcast read
            float cB = wl[idx];                               // L_B[lane][k]
            off += 64 - k;
            float bii = bcast(cB, k);
            float inv = __builtin_amdgcn_rcpf(bii);
            // freeze: lanes <= k stop updating -> their row regs keep their
            // own row's unscaled W values; fro recovered in the epilogue.
            float tt = (lane > k) ? (cB * inv) : 0.0f;
#pragma unroll
            for (int c2 = 0; c2 <= k; ++c2) {
                float u = bcast(rA[c2], k);              // frozen row k (uniform)
                rA[c2] = __builtin_fmaf(-tt, u, rA[c2]); // update rows > k
            }
        }

        // Epilogue: row `lane` of W (unscaled) sits frozen in rA[0..lane];
        // scale by rcp(L_B[lane][lane]) read from packed column start.
        const int m = lane;
        const int offm = (m * (129 - m)) >> 1;
        float dm = wl[offm];
        float invm = __builtin_amdgcn_rcpf(dm);
        float fr = 0.0f;
#pragma unroll
        for (int c = 0; c < 64; ++c) {
            float v = (c <= lane) ? rA[c] : 0.0f;  // c>lane regs hold non-W data
            fr = __builtin_fmaf(v, v, fr);
        }
        fr = fr * invm * invm;
#pragma unroll
        for (int s = 1; s < 64; s <<= 1) fr += __shfl_xor(fr, s, 64);

        float sdetB = __builtin_sqrtf(detB);
        float sdetA = __builtin_sqrtf(detA);
        float logdet = __builtin_logf((sdetA + EPS) / (sdetB + EPS));
        kl = 0.5f * (fr - 64.0f + logdet);
    }

    __shared__ float sred[4];
    if (lane == 0) sred[waveInBlock] = kl;
    __syncthreads();
    if (threadIdx.x == 0) {
        float s = sred[0] + sred[1] + sred[2] + sred[3];
        atomicAdd(out + 1, -s);
    }
}

// Encoded: 32x32 Cholesky (sqrt-det) + trace. Two matrices per wave (lanes
// 0-31 / 32-63); broadcasts via two static readlanes + select on the half.
// (round-3 version, unchanged: ~34 us standalone)
__global__ __launch_bounds__(256, 1) void vae_enc_kernel(const float* __restrict__ enc,
                                                         float* __restrict__ out,
                                                         int nmats) {
    const int lane = threadIdx.x & 63;
    const int r = lane & 31;
    const bool hi = lane >= 32;
    const int wv = (int)(blockIdx.x * 4 + (threadIdx.x >> 6));
    const int mat = wv * 2 + (hi ? 1 : 0);

    float kl = 0.0f;
    if (mat < nmats) {
        const float* M = enc + (size_t)mat * 1024;
        float rm[32];
        {
            const float4* pm = (const float4*)(M + r * 32);
#pragma unroll
            for (int i = 0; i < 8; ++i) {
                float4 v = pm[i];
                rm[4 * i + 0] = v.x; rm[4 * i + 1] = v.y;
                rm[4 * i + 2] = v.z; rm[4 * i + 3] = v.w;
            }
        }

        float tr = 0.0f;
#pragma unroll
        for (int i = 0; i < 32; ++i)
            if (i == r) tr = rm[i];
#pragma unroll
        for (int m = 1; m < 32; m <<= 1)
            tr += __shfl_xor(tr, m, 64);

        float det = 1.0f;
#pragma unroll
        for (int k = 0; k < 32; ++k) {
            float a0 = bcast(rm[k], k);
            float a1 = bcast(rm[k], k + 32);
            float akk = hi ? a1 : a0;
            det *= akk;
            float inv = __builtin_amdgcn_rsqf(akk);
            rm[k] *= inv;
#pragma unroll
            for (int j = k + 1; j < 32; ++j) {
                float l0 = bcast(rm[k], j);
                float l1 = bcast(rm[k], j + 32);
                float ljk = hi ? l1 : l0;
                rm[j] = __builtin_fmaf(-rm[k], ljk, rm[j]);
            }
        }

        float sdet = __builtin_sqrtf(det);
        float logdet = __builtin_logf((sdet + EPS) / (1.0f + EPS));
        kl = 0.5f * (tr - 32.0f + logdet);
    }

    __shared__ float sred[8];
    if (r == 0) sred[threadIdx.x >> 5] = kl;
    __syncthreads();
    if (threadIdx.x == 0) {
        float s = 0.0f;
#pragma unroll
        for (int i = 0; i < 8; ++i) s += sred[i];
        atomicAdd(out + 2, -s);
    }
}

__global__ void vae_init_kernel(float* __restrict__ out) {
    if (threadIdx.x < 3) out[threadIdx.x] = 0.0f;
}

__global__ void vae_final_kernel(float* __restrict__ out) {
    if (threadIdx.x == 0) out[0] = out[1] + out[2];
}

extern "C" void kernel_launch(void* const* d_in, const int* in_sizes, int n_in,
                              void* d_out, int out_size, void* d_ws, size_t ws_size,
                              hipStream_t stream) {
    const float* recon = (const float*)d_in[0];
    const float* orig = (const float*)d_in[1];
    const float* enc = (const float*)d_in[2];
    float* out = (float*)d_out;

    const int npairs = in_sizes[0] / 4096;   // 8192
    const int nmats = in_sizes[2] / 1024;    // 8192

    vae_init_kernel<<<1, 64, 0, stream>>>(out);

    const int rec_blocks = (npairs + 3) / 4;          // 4 waves/block, 1 pair/wave
    vae_rec_kernel<<<rec_blocks, 256, 0, stream>>>(recon, orig, out, npairs);

    const int enc_blocks = (nmats + 7) / 8;           // 8 matrices/block (2 per wave)
    vae_enc_kernel<<<enc_blocks, 256, 0, stream>>>(enc, out, nmats);

    vae_final_kernel<<<1, 64, 0, stream>>>(out);
}